// Round 1
// baseline (371.209 us; speedup 1.0000x reference)
//
#include <hip/hip_runtime.h>
#include <hip/hip_bf16.h>
#include <math.h>

#define CHANNEL 8
#define KDIM 16
#define DFULL 128
#define MNBR 32
#define ROUT_IT 3

// ---------------------------------------------------------------------------
// K1: out_row = normalize_per_capsule(relu(x @ W^T + b)), one row per lane.
// W/b indices are wave-uniform -> scalar loads; x row per-lane float4 (L1-hot).
// Also writes the zero pad row at index n.
// ---------------------------------------------------------------------------
__global__ __launch_bounds__(256) void fc_norm_kernel(
    const float* __restrict__ x, const float* __restrict__ W,
    const float* __restrict__ b, float* __restrict__ z, int n) {
  int r = blockIdx.x * 256 + threadIdx.x;
  if (r > n) return;
  float4* orow = (float4*)(z + (size_t)r * DFULL);
  if (r == n) {  // pad row = zeros
    float4 z4 = make_float4(0.f, 0.f, 0.f, 0.f);
#pragma unroll
    for (int i = 0; i < DFULL / 4; ++i) orow[i] = z4;
    return;
  }
  const float4* xr = (const float4*)(x + (size_t)r * DFULL);
  for (int c = 0; c < CHANNEL; ++c) {
    float acc[KDIM];
#pragma unroll
    for (int j = 0; j < KDIM; ++j) acc[j] = b[c * KDIM + j];  // uniform -> s_load
    for (int i4 = 0; i4 < DFULL / 4; ++i4) {
      float4 xv = xr[i4];
#pragma unroll
      for (int j = 0; j < KDIM; ++j) {
        // uniform index -> scalar loads of W
        const float4 wv = *(const float4*)(W + (size_t)(c * KDIM + j) * DFULL + i4 * 4);
        acc[j] = fmaf(xv.x, wv.x, fmaf(xv.y, wv.y, fmaf(xv.z, wv.z, fmaf(xv.w, wv.w, acc[j]))));
      }
    }
    float ss = 0.f;
#pragma unroll
    for (int j = 0; j < KDIM; ++j) {
      acc[j] = fmaxf(acc[j], 0.f);
      ss += acc[j] * acc[j];
    }
    float scale = 1.0f / fmaxf(sqrtf(ss), 1e-12f);
#pragma unroll
    for (int j4 = 0; j4 < KDIM / 4; ++j4) {
      float4 v;
      v.x = acc[j4 * 4 + 0] * scale;
      v.y = acc[j4 * 4 + 1] * scale;
      v.z = acc[j4 * 4 + 2] * scale;
      v.w = acc[j4 * 4 + 3] * scale;
      orow[c * (KDIM / 4) + j4] = v;
    }
  }
}

// ---------------------------------------------------------------------------
// K2: dynamic routing, one node per 256-thread block.
// LDS: neighbors padded to stride 132 (4-way max bank aliasing on p-phase,
// conflict-free on u-phase column walk).
// ---------------------------------------------------------------------------
#define NBSTRIDE 132

__global__ __launch_bounds__(256) void routing_kernel(
    const float* __restrict__ z, const int* __restrict__ nid,
    float* __restrict__ out, int n) {
  __shared__ float nb[MNBR * NBSTRIDE];
  __shared__ float xl[DFULL];
  __shared__ float ul[DFULL];
  __shared__ float pl[MNBR * CHANNEL];
  __shared__ float sl[MNBR * CHANNEL];

  int node = blockIdx.x;
  int t = threadIdx.x;

  // stage neighbors: 1024 float4 loads, 4 per thread
  for (int q = t; q < MNBR * (DFULL / 4); q += 256) {
    int m = q >> 5;       // q / 32
    int o4 = q & 31;      // float4 index within row
    int row = nid[node * MNBR + m];
    float4 v = *(const float4*)(z + (size_t)row * DFULL + o4 * 4);
    *(float4*)(nb + m * NBSTRIDE + o4 * 4) = v;
  }
  if (t < DFULL) {
    float v = z[(size_t)node * DFULL + t];
    xl[t] = v;
    ul[t] = v;
  }
  __syncthreads();

  const int m = t >> 3;  // 0..31
  const int c = t & 7;   // 0..7
  const int c2 = (t & 127) >> 4;  // used in u-phase
  const int k = t & 15;

  for (int it = 0; it < ROUT_IT; ++it) {
    // ---- p[m][c] = sum_k u[c][k] * nb[m][c][k]
    {
      float s = 0.f;
      const float* nbr = nb + m * NBSTRIDE + c * KDIM;
      const float* ur = ul + c * KDIM;
#pragma unroll
      for (int kk = 0; kk < KDIM; ++kk) s += ur[kk] * nbr[kk];
      pl[t] = s;
    }
    __syncthreads();
    // ---- softmax over c (each thread redundantly reduces its m-row)
    {
      float mx = -1e30f;
#pragma unroll
      for (int cc = 0; cc < CHANNEL; ++cc) mx = fmaxf(mx, pl[m * CHANNEL + cc]);
      float den = 0.f;
#pragma unroll
      for (int cc = 0; cc < CHANNEL; ++cc) den += __expf(pl[m * CHANNEL + cc] - mx);
      sl[t] = __expf(pl[t] - mx) / den;
    }
    __syncthreads();
    // ---- u[c][k] = x[c][k] + sum_m s[m][c] * nb[m][c][k]; normalize unless last
    if (t < DFULL) {
      float acc = xl[t];
      const float* nbc = nb + c2 * KDIM + k;
      const float* sc = sl + c2;
#pragma unroll
      for (int mm = 0; mm < MNBR; ++mm)
        acc = fmaf(sc[mm * CHANNEL], nbc[mm * NBSTRIDE], acc);
      if (it == ROUT_IT - 1) {
        out[(size_t)node * DFULL + t] = acc;
      } else {
        float ss = acc * acc;
#pragma unroll
        for (int d = 1; d < KDIM; d <<= 1) ss += __shfl_xor(ss, d);
        float scale = 1.0f / fmaxf(sqrtf(ss), 1e-12f);
        ul[t] = acc * scale;
      }
    }
    __syncthreads();
  }
}

// ---------------------------------------------------------------------------
extern "C" void kernel_launch(void* const* d_in, const int* in_sizes, int n_in,
                              void* d_out, int out_size, void* d_ws, size_t ws_size,
                              hipStream_t stream) {
  const float* x = (const float*)d_in[0];
  const float* W = (const float*)d_in[1];
  const float* b = (const float*)d_in[2];
  const int* nid = (const int*)d_in[3];
  float* out = (float*)d_out;

  int n = in_sizes[0] / DFULL;  // 50000
  float* z = (float*)d_ws;      // (n+1) x 128 f32 normalized-feature table

  int rows = n + 1;
  int g1 = (rows + 255) / 256;
  fc_norm_kernel<<<g1, 256, 0, stream>>>(x, W, b, z, n);
  routing_kernel<<<n, 256, 0, stream>>>(z, nid, out, n);
}

// Round 2
// 266.170 us; speedup vs baseline: 1.3946x; 1.3946x over previous
//
#include <hip/hip_runtime.h>
#include <hip/hip_bf16.h>
#include <math.h>

#define CHANNEL 8
#define KDIM 16
#define DFULL 128
#define MNBR 32
#define ROUT_IT 3

typedef __attribute__((ext_vector_type(4))) float f32x4;
typedef __attribute__((ext_vector_type(8))) short short8;

__device__ inline ushort f2bf(float f) {
  // round-to-nearest-even f32 -> bf16 (no NaN handling needed here)
  unsigned u = __float_as_uint(f);
  unsigned r = (u + 0x7fffu + ((u >> 16) & 1u)) >> 16;
  return (ushort)r;
}
__device__ inline float bf2f(ushort u) {
  return __uint_as_float(((unsigned)u) << 16);
}
__device__ inline float bflo(unsigned d) { return __uint_as_float(d << 16); }
__device__ inline float bfhi(unsigned d) { return __uint_as_float(d & 0xffff0000u); }

__device__ inline short8 ld8(const ushort* p) {  // 16 bytes via two 8B loads (8B-aligned)
  uint2 a = *(const uint2*)p;
  uint2 b = *(const uint2*)(p + 4);
  union { unsigned u[4]; short8 v; } U;
  U.u[0] = a.x; U.u[1] = a.y; U.u[2] = b.x; U.u[3] = b.y;
  return U.v;
}

// ---------------------------------------------------------------------------
// K1: z16[r] = bf16( normalize_per_capsule( relu(x @ W^T + b) ) ), row n = 0.
// MFMA bf16, 64 rows/block, K=128 single pass. LDS strides padded (132) so
// A/B fragment reads are ~2-way (free) bank aliased.
// ---------------------------------------------------------------------------
#define TM1 64
#define LSTR 132  // ushort stride: 264B/row -> 66 dwords === 2 (mod 32)

__global__ __launch_bounds__(256) void fc_mfma_kernel(
    const float* __restrict__ x, const float* __restrict__ W,
    const float* __restrict__ bias, ushort* __restrict__ z16, int n) {
  __shared__ ushort xs[TM1 * LSTR];    // 16.9 KB
  __shared__ ushort wsh[128 * LSTR];   // 33.8 KB
  const int t = threadIdx.x;
  const int r0 = blockIdx.x * TM1;

  // stage W (128x128 f32 -> bf16): thread covers row t>>1, half t&1 (64 vals)
  {
    int row = t >> 1, half = t & 1;
    const float4* src = (const float4*)(W + row * 128 + half * 64);
    ushort* dst = wsh + row * LSTR + half * 64;
#pragma unroll
    for (int j = 0; j < 16; ++j) {
      float4 v = src[j];
      ushort4 o = {f2bf(v.x), f2bf(v.y), f2bf(v.z), f2bf(v.w)};
      *(ushort4*)(dst + j * 4) = o;
    }
  }
  // stage x rows r0..r0+63: thread covers row t>>2, quarter t&3 (32 vals)
  {
    int rb = t >> 2, q = t & 3;
    int row = r0 + rb;
    ushort* dst = xs + rb * LSTR + q * 32;
    if (row < n) {
      const float4* src = (const float4*)(x + (size_t)row * 128 + q * 32);
#pragma unroll
      for (int j = 0; j < 8; ++j) {
        float4 v = src[j];
        ushort4 o = {f2bf(v.x), f2bf(v.y), f2bf(v.z), f2bf(v.w)};
        *(ushort4*)(dst + j * 4) = o;
      }
    } else {
      ushort4 zz = {0, 0, 0, 0};
#pragma unroll
      for (int j = 0; j < 8; ++j) *(ushort4*)(dst + j * 4) = zz;
    }
  }
  __syncthreads();

  const int lane = t & 63, w = t >> 6;
  const int L = lane & 15, H = lane >> 4;

  f32x4 acc[8];
#pragma unroll
  for (int j = 0; j < 8; ++j) {
    float bv = bias[j * 16 + L];
    acc[j] = (f32x4){bv, bv, bv, bv};
  }
  const ushort* arow = xs + (w * 16 + L) * LSTR;
#pragma unroll
  for (int kk = 0; kk < 4; ++kk) {
    const int ko = kk * 32 + H * 8;
    short8 af = ld8(arow + ko);
#pragma unroll
    for (int j = 0; j < 8; ++j) {
      short8 bf = ld8(wsh + (j * 16 + L) * LSTR + ko);
      acc[j] = __builtin_amdgcn_mfma_f32_16x16x32_bf16(af, bf, acc[j], 0, 0, 0);
    }
  }
  // epilogue: relu, per-(row,capsule) L2 norm (16 cols = 16 lanes), bf16 store
  const int rbase = r0 + w * 16 + H * 4;
#pragma unroll
  for (int j = 0; j < 8; ++j) {
#pragma unroll
    for (int r = 0; r < 4; ++r) {
      float v = fmaxf(acc[j][r], 0.f);
      float sq = v * v;
      sq += __shfl_xor(sq, 1);
      sq += __shfl_xor(sq, 2);
      sq += __shfl_xor(sq, 4);
      sq += __shfl_xor(sq, 8);
      float scale = 1.f / fmaxf(sqrtf(sq), 1e-12f);
      int row = rbase + r;
      if (row < n)
        z16[(size_t)row * DFULL + j * 16 + L] = f2bf(v * scale);
      else if (row == n)
        z16[(size_t)row * DFULL + j * 16 + L] = 0;  // pad row = zeros
    }
  }
}

// ---------------------------------------------------------------------------
// K2: dynamic routing, one node per 256-thread block, bf16 neighbor tile.
// nb row stride 132 ushorts (264B): p-phase b64 reads 2-way (free),
// u-phase u16 column reads conflict-free. Softmax without max (|p|<=1),
// exp computed in-register during p-phase.
// ---------------------------------------------------------------------------
#define NBS 132
#define ULS 20  // f32 stride per capsule in ul/xl (banks 20c mod 32 distinct)

__global__ __launch_bounds__(256) void routing_kernel(
    const ushort* __restrict__ z16, const int* __restrict__ nid,
    float* __restrict__ out, int n) {
  __shared__ __align__(16) ushort nb[MNBR * NBS];  // 8448 B
  __shared__ float xl[CHANNEL * ULS];
  __shared__ float ul[CHANNEL * ULS];
  __shared__ float pl[MNBR * CHANNEL];
  __shared__ float sl[MNBR * CHANNEL];

  const int node = blockIdx.x;
  const int t = threadIdx.x;

  // ---- stage neighbors (bf16): 8 threads per neighbor row, 32B each
  {
    int m = t >> 3, seg = t & 7;
    int row = nid[node * MNBR + m];
    const uint4* src = (const uint4*)(z16 + (size_t)row * DFULL + seg * 16);
    uint4 A = src[0], B = src[1];
    ushort* dst = nb + m * NBS + seg * 16;
    *(uint2*)(dst + 0) = make_uint2(A.x, A.y);
    *(uint2*)(dst + 4) = make_uint2(A.z, A.w);
    *(uint2*)(dst + 8) = make_uint2(B.x, B.y);
    *(uint2*)(dst + 12) = make_uint2(B.z, B.w);
  }
  if (t < DFULL) {
    int c2 = t >> 4, k = t & 15;
    float v = bf2f(z16[(size_t)node * DFULL + t]);
    xl[c2 * ULS + k] = v;
    ul[c2 * ULS + k] = v;
  }
  __syncthreads();

  const int m = t >> 3;  // 0..31
  const int c = t & 7;   // 0..7
  const int c2 = (t & 127) >> 4;
  const int k = t & 15;

  for (int it = 0; it < ROUT_IT; ++it) {
    // ---- p[m][c] = <u[c], nb[m][c]> ; e = exp(p) (|p| <= 1, no max needed)
    float e;
    {
      const ushort* nbp = nb + m * NBS + c * 16;
      uint2 q0 = *(const uint2*)(nbp + 0);
      uint2 q1 = *(const uint2*)(nbp + 4);
      uint2 q2 = *(const uint2*)(nbp + 8);
      uint2 q3 = *(const uint2*)(nbp + 12);
      const float4* up = (const float4*)(ul + c * ULS);
      float4 u0 = up[0], u1 = up[1], u2 = up[2], u3 = up[3];
      float s = 0.f;
      s = fmaf(u0.x, bflo(q0.x), s); s = fmaf(u0.y, bfhi(q0.x), s);
      s = fmaf(u0.z, bflo(q0.y), s); s = fmaf(u0.w, bfhi(q0.y), s);
      s = fmaf(u1.x, bflo(q1.x), s); s = fmaf(u1.y, bfhi(q1.x), s);
      s = fmaf(u1.z, bflo(q1.y), s); s = fmaf(u1.w, bfhi(q1.y), s);
      s = fmaf(u2.x, bflo(q2.x), s); s = fmaf(u2.y, bfhi(q2.x), s);
      s = fmaf(u2.z, bflo(q2.y), s); s = fmaf(u2.w, bfhi(q2.y), s);
      s = fmaf(u3.x, bflo(q3.x), s); s = fmaf(u3.y, bfhi(q3.x), s);
      s = fmaf(u3.z, bflo(q3.y), s); s = fmaf(u3.w, bfhi(q3.y), s);
      e = __expf(s);
      pl[m * CHANNEL + c] = e;
    }
    __syncthreads();
    // ---- softmax over c: den from 2 b128 reads (broadcast), s = e/den
    {
      float4 p0 = *(const float4*)(pl + m * CHANNEL);
      float4 p1 = *(const float4*)(pl + m * CHANNEL + 4);
      float den = ((p0.x + p0.y) + (p0.z + p0.w)) + ((p1.x + p1.y) + (p1.z + p1.w));
      sl[m * CHANNEL + c] = e * __builtin_amdgcn_rcpf(den);
    }
    __syncthreads();
    // ---- u[c][k] = x[c][k] + sum_m s[m][c]*nb[m][c][k]; normalize unless last
    if (t < DFULL) {
      float acc = xl[c2 * ULS + k];
      const ushort* col = nb + c2 * 16 + k;
      const float* sc = sl + c2;
#pragma unroll
      for (int mm = 0; mm < MNBR; ++mm)
        acc = fmaf(sc[mm * CHANNEL], bf2f(col[mm * NBS]), acc);
      if (it == ROUT_IT - 1) {
        out[(size_t)node * DFULL + t] = acc;
      } else {
        float ss = acc * acc;
        ss += __shfl_xor(ss, 1);
        ss += __shfl_xor(ss, 2);
        ss += __shfl_xor(ss, 4);
        ss += __shfl_xor(ss, 8);
        float scale = 1.0f / fmaxf(sqrtf(ss), 1e-12f);
        ul[c2 * ULS + k] = acc * scale;
      }
    }
    __syncthreads();
  }
}

// ---------------------------------------------------------------------------
extern "C" void kernel_launch(void* const* d_in, const int* in_sizes, int n_in,
                              void* d_out, int out_size, void* d_ws, size_t ws_size,
                              hipStream_t stream) {
  const float* x = (const float*)d_in[0];
  const float* W = (const float*)d_in[1];
  const float* b = (const float*)d_in[2];
  const int* nid = (const int*)d_in[3];
  float* out = (float*)d_out;

  int n = in_sizes[0] / DFULL;      // 50000
  ushort* z16 = (ushort*)d_ws;      // (n+1..padded) x 128 bf16 table

  int g1 = (n + 1 + TM1 - 1) / TM1;  // covers rows 0..n (pad row n zeroed)
  fc_mfma_kernel<<<g1, 256, 0, stream>>>(x, W, b, z16, n);
  routing_kernel<<<n, 256, 0, stream>>>(z16, nid, out, n);
}

// Round 3
// 236.076 us; speedup vs baseline: 1.5724x; 1.1275x over previous
//
#include <hip/hip_runtime.h>
#include <hip/hip_bf16.h>
#include <math.h>

#define CHANNEL 8
#define KDIM 16
#define DFULL 128
#define MNBR 32
#define ROUT_IT 3
#define TM1 64

typedef __attribute__((ext_vector_type(4))) float f32x4;
typedef __attribute__((ext_vector_type(2))) float f32x2;
typedef __attribute__((ext_vector_type(8))) short short8;

__device__ inline ushort f2bf(float f) {  // RNE f32->bf16
  unsigned u = __float_as_uint(f);
  return (ushort)((u + 0x7fffu + ((u >> 16) & 1u)) >> 16);
}
__device__ inline float bf2f(ushort u) { return __uint_as_float(((unsigned)u) << 16); }
__device__ inline float bflo(unsigned d) { return __uint_as_float(d << 16); }
__device__ inline float bfhi(unsigned d) { return __uint_as_float(d & 0xffff0000u); }
__device__ inline f32x2 pkfma(f32x2 a, f32x2 b, f32x2 c) {
  return __builtin_elementwise_fma(a, b, c);  // -> v_pk_fma_f32
}

// ---------------------------------------------------------------------------
// K0: convert W (128x128 f32) once into the padded bf16 LDS image (stride 136).
// ---------------------------------------------------------------------------
#define WSTR 136
__global__ __launch_bounds__(256) void wconv_kernel(const float* __restrict__ W,
                                                    ushort* __restrict__ wbf) {
  int task = blockIdx.x * 256 + threadIdx.x;  // 512 tasks: 128 rows x 4 quarters
  if (task >= 512) return;
  int row = task >> 2, q = task & 3;
  const float4* src = (const float4*)(W + row * 128 + q * 32);
  ushort* dst = wbf + row * WSTR + q * 32;
#pragma unroll
  for (int j = 0; j < 8; ++j) {
    float4 v = src[j];
    ushort4 o = {f2bf(v.x), f2bf(v.y), f2bf(v.z), f2bf(v.w)};
    *(ushort4*)(dst + j * 4) = o;
  }
}

// ---------------------------------------------------------------------------
// K1: z16[r] = bf16( normalize_per_capsule( relu(x @ W^T + b) ) ), row n = 0.
// W staged as a plain uint4 image copy (pre-converted). Epilogue via LDS
// transpose (no shuffles). xs aliases ys (xs dead after last MFMA read).
// ---------------------------------------------------------------------------
__global__ __launch_bounds__(256) void fc_mfma_kernel(
    const float* __restrict__ x, const ushort* __restrict__ wbf,
    const float* __restrict__ bias, ushort* __restrict__ z16, int n) {
  __shared__ __align__(16) char smem[WSTR * 128 * 2 + 132 * 64 * 4];  // 34816+33792
  ushort* wsh = (ushort*)smem;
  ushort* xs = (ushort*)(smem + WSTR * 128 * 2);  // aliases ys (barrier-separated)
  float* ys = (float*)(smem + WSTR * 128 * 2);

  const int t = threadIdx.x;
  const int r0 = blockIdx.x * TM1;

  // stage W image: 2176 uint4
  {
    const uint4* ws4 = (const uint4*)wbf;
    uint4* wd4 = (uint4*)wsh;
#pragma unroll
    for (int i = 0; i < 9; ++i) {
      int idx = t + i * 256;
      if (idx < (WSTR * 128 * 2) / 16) wd4[idx] = ws4[idx];
    }
  }
  // stage x rows r0..r0+63 (bf16, stride 136)
  {
    int rb = t >> 2, q = t & 3;
    int row = r0 + rb;
    ushort* dst = xs + rb * WSTR + q * 32;
    if (row < n) {
      const float4* src = (const float4*)(x + (size_t)row * 128 + q * 32);
#pragma unroll
      for (int j = 0; j < 8; ++j) {
        float4 v = src[j];
        ushort4 o = {f2bf(v.x), f2bf(v.y), f2bf(v.z), f2bf(v.w)};
        *(ushort4*)(dst + j * 4) = o;
      }
    } else {
      ushort4 zz = {0, 0, 0, 0};
#pragma unroll
      for (int j = 0; j < 8; ++j) *(ushort4*)(dst + j * 4) = zz;
    }
  }
  __syncthreads();

  const int lane = t & 63, w = t >> 6;
  const int L = lane & 15, H = lane >> 4;

  f32x4 acc[8];
#pragma unroll
  for (int j = 0; j < 8; ++j) {
    float bv = bias[j * 16 + L];
    acc[j] = (f32x4){bv, bv, bv, bv};
  }
  const ushort* arow = xs + (w * 16 + L) * WSTR;
#pragma unroll
  for (int kk = 0; kk < 4; ++kk) {
    const int ko = kk * 32 + H * 8;
    short8 af = *(const short8*)(arow + ko);
#pragma unroll
    for (int j = 0; j < 8; ++j) {
      short8 bfr = *(const short8*)(wsh + (j * 16 + L) * WSTR + ko);
      acc[j] = __builtin_amdgcn_mfma_f32_16x16x32_bf16(af, bfr, acc[j], 0, 0, 0);
    }
  }
  __syncthreads();  // xs reads complete before ys overwrite

  // scatter relu'd f32 tile to ys [local_row][d], stride 132
  const int lr = w * 16 + H * 4;
#pragma unroll
  for (int j = 0; j < 8; ++j)
#pragma unroll
    for (int r = 0; r < 4; ++r)
      ys[(lr + r) * 132 + j * 16 + L] = fmaxf(acc[j][r], 0.f);
  __syncthreads();

  // norm + bf16 store: 512 (row,capsule) tasks, 2 per thread
#pragma unroll
  for (int p = 0; p < 2; ++p) {
    int task = t + p * 256;
    int row = task >> 3, cc = task & 7;
    const float4* yr = (const float4*)(ys + row * 132 + cc * 16);
    float4 a = yr[0], b = yr[1], c4 = yr[2], d4 = yr[3];
    float ss = a.x * a.x;
    ss = fmaf(a.y, a.y, ss); ss = fmaf(a.z, a.z, ss); ss = fmaf(a.w, a.w, ss);
    ss = fmaf(b.x, b.x, ss); ss = fmaf(b.y, b.y, ss); ss = fmaf(b.z, b.z, ss);
    ss = fmaf(b.w, b.w, ss); ss = fmaf(c4.x, c4.x, ss); ss = fmaf(c4.y, c4.y, ss);
    ss = fmaf(c4.z, c4.z, ss); ss = fmaf(c4.w, c4.w, ss); ss = fmaf(d4.x, d4.x, ss);
    ss = fmaf(d4.y, d4.y, ss); ss = fmaf(d4.z, d4.z, ss); ss = fmaf(d4.w, d4.w, ss);
    float scale = 1.f / fmaxf(sqrtf(ss), 1e-12f);
    int grow = r0 + row;
    if (grow < n) {
      ushort* dst = z16 + (size_t)grow * DFULL + cc * 16;
      ushort4 o0 = {f2bf(a.x * scale), f2bf(a.y * scale), f2bf(a.z * scale), f2bf(a.w * scale)};
      ushort4 o1 = {f2bf(b.x * scale), f2bf(b.y * scale), f2bf(b.z * scale), f2bf(b.w * scale)};
      ushort4 o2 = {f2bf(c4.x * scale), f2bf(c4.y * scale), f2bf(c4.z * scale), f2bf(c4.w * scale)};
      ushort4 o3 = {f2bf(d4.x * scale), f2bf(d4.y * scale), f2bf(d4.z * scale), f2bf(d4.w * scale)};
      *(ushort4*)(dst + 0) = o0;
      *(ushort4*)(dst + 4) = o1;
      *(ushort4*)(dst + 8) = o2;
      *(ushort4*)(dst + 12) = o3;
    } else if (grow == n) {  // pad row = zeros
      ushort4 zz = {0, 0, 0, 0};
      ushort* dst = z16 + (size_t)grow * DFULL + cc * 16;
      *(ushort4*)(dst + 0) = zz;
      *(ushort4*)(dst + 4) = zz;
      *(ushort4*)(dst + 8) = zz;
      *(ushort4*)(dst + 12) = zz;
    }
  }
}

// ---------------------------------------------------------------------------
// K2: routing. Thread (m = t&31, c = t>>5) holds nb[m][c][0..15] in registers
// (used for p all 3 iters); s stays in-register between softmax and slT write.
// u-phase reads f32 nbT rows + slT rows with packed f32 fma.
// ---------------------------------------------------------------------------
#define NTS 36  // nbT/slT row stride (f32): 144B, 16B-aligned, +4 bank shift
#define PLS 10
#define ULS 20

__global__ __launch_bounds__(256) void routing_kernel(
    const ushort* __restrict__ z16, const int* __restrict__ nid,
    float* __restrict__ out, int n) {
  __shared__ __align__(16) float nbT[DFULL * NTS];     // 18432 B
  __shared__ __align__(16) float slT[CHANNEL * NTS];   // 1152 B
  __shared__ __align__(16) float ul[CHANNEL * ULS];    // 640 B
  __shared__ __align__(16) float pl[MNBR * PLS];       // 1280 B

  const int node = blockIdx.x;
  const int t = threadIdx.x;
  const int m = t & 31;
  const int c = t >> 5;

  // ---- stage: thread owns neighbor m, channel c (16 bf16 values -> f32 regs)
  int row = nid[node * MNBR + m];
  const uint4* src = (const uint4*)(z16 + (size_t)row * DFULL + c * KDIM);
  uint4 A = src[0], B = src[1];
  f32x2 nbr[8];
  nbr[0] = (f32x2){bflo(A.x), bfhi(A.x)};
  nbr[1] = (f32x2){bflo(A.y), bfhi(A.y)};
  nbr[2] = (f32x2){bflo(A.z), bfhi(A.z)};
  nbr[3] = (f32x2){bflo(A.w), bfhi(A.w)};
  nbr[4] = (f32x2){bflo(B.x), bfhi(B.x)};
  nbr[5] = (f32x2){bflo(B.y), bfhi(B.y)};
  nbr[6] = (f32x2){bflo(B.z), bfhi(B.z)};
  nbr[7] = (f32x2){bflo(B.w), bfhi(B.w)};
  {
    float* col = nbT + (c * KDIM) * NTS + m;
#pragma unroll
    for (int k = 0; k < 16; ++k) col[k * NTS] = nbr[k >> 1][k & 1];
  }
  float xk = 0.f;
  if (t < DFULL) {
    xk = bf2f(z16[(size_t)node * DFULL + t]);
    ul[(t >> 4) * ULS + (t & 15)] = xk;
  }
  __syncthreads();

  for (int it = 0; it < ROUT_IT; ++it) {
    // ---- p = <u_c, nb_mc> from registers; e = exp(p) (|p|<=1, no max)
    const float4* up = (const float4*)(ul + c * ULS);
    float4 u0 = up[0], u1 = up[1], u2 = up[2], u3 = up[3];
    f32x2 a0 = {0.f, 0.f}, a1 = {0.f, 0.f};
    a0 = pkfma(nbr[0], (f32x2){u0.x, u0.y}, a0);
    a1 = pkfma(nbr[1], (f32x2){u0.z, u0.w}, a1);
    a0 = pkfma(nbr[2], (f32x2){u1.x, u1.y}, a0);
    a1 = pkfma(nbr[3], (f32x2){u1.z, u1.w}, a1);
    a0 = pkfma(nbr[4], (f32x2){u2.x, u2.y}, a0);
    a1 = pkfma(nbr[5], (f32x2){u2.z, u2.w}, a1);
    a0 = pkfma(nbr[6], (f32x2){u3.x, u3.y}, a0);
    a1 = pkfma(nbr[7], (f32x2){u3.z, u3.w}, a1);
    f32x2 aa = a0 + a1;
    float e = __expf(aa.x + aa.y);
    pl[m * PLS + c] = e;
    __syncthreads();
    // ---- softmax over c: denominator via packed adds; s stays in-register
    const f32x2* pr = (const f32x2*)(pl + m * PLS);
    f32x2 d0 = pr[0] + pr[1];
    f32x2 d1 = pr[2] + pr[3];
    f32x2 dd = d0 + d1;
    float s = e * __builtin_amdgcn_rcpf(dd.x + dd.y);
    slT[c * NTS + m] = s;
    __syncthreads();
    // ---- u[d] = x[d] + sum_m s[m][c]*nbT[d][m]; normalize unless last iter
    if (t < DFULL) {
      const f32x2* nr = (const f32x2*)(nbT + t * NTS);
      const f32x2* sr = (const f32x2*)(slT + (t >> 4) * NTS);
      f32x2 A0 = {0.f, 0.f}, A1 = {0.f, 0.f};
#pragma unroll
      for (int j = 0; j < 16; j += 2) {
        A0 = pkfma(nr[j], sr[j], A0);
        A1 = pkfma(nr[j + 1], sr[j + 1], A1);
      }
      f32x2 S = A0 + A1;
      float u = S.x + S.y + xk;
      if (it == ROUT_IT - 1) {
        out[(size_t)node * DFULL + t] = u;
      } else {
        float ss = u * u;
        ss += __shfl_xor(ss, 1);
        ss += __shfl_xor(ss, 2);
        ss += __shfl_xor(ss, 4);
        ss += __shfl_xor(ss, 8);
        float scale = 1.f / fmaxf(sqrtf(ss), 1e-12f);
        ul[(t >> 4) * ULS + (t & 15)] = u * scale;
      }
    }
    __syncthreads();
  }
}

// ---------------------------------------------------------------------------
extern "C" void kernel_launch(void* const* d_in, const int* in_sizes, int n_in,
                              void* d_out, int out_size, void* d_ws, size_t ws_size,
                              hipStream_t stream) {
  const float* x = (const float*)d_in[0];
  const float* W = (const float*)d_in[1];
  const float* b = (const float*)d_in[2];
  const int* nid = (const int*)d_in[3];
  float* out = (float*)d_out;

  int n = in_sizes[0] / DFULL;  // 50000
  int g1 = (n + 1 + TM1 - 1) / TM1;  // 782: covers rows 0..n (pad row n zeroed)
  size_t zrows = (size_t)g1 * TM1;   // 50048

  ushort* z16 = (ushort*)d_ws;                 // zrows x 128 bf16 table
  ushort* wbf = (ushort*)d_ws + zrows * DFULL; // 128 x 136 bf16 W image

  wconv_kernel<<<2, 256, 0, stream>>>(W, wbf);
  fc_mfma_kernel<<<g1, 256, 0, stream>>>(x, wbf, b, z16, n);
  routing_kernel<<<n, 256, 0, stream>>>(z16, nid, out, n);
}

// Round 4
// 187.366 us; speedup vs baseline: 1.9812x; 1.2600x over previous
//
#include <hip/hip_runtime.h>
#include <hip/hip_bf16.h>
#include <math.h>

#define CHANNEL 8
#define KDIM 16
#define DFULL 128
#define MNBR 32
#define ROUT_IT 3
#define TM1 64

typedef __attribute__((ext_vector_type(4))) float f32x4;
typedef __attribute__((ext_vector_type(2))) float f32x2;
typedef __attribute__((ext_vector_type(8))) short short8;

__device__ inline float bf2f(ushort u) { return __uint_as_float(((unsigned)u) << 16); }
__device__ inline float bflo(unsigned d) { return __uint_as_float(d << 16); }
__device__ inline float bfhi(unsigned d) { return __uint_as_float(d & 0xffff0000u); }
__device__ inline f32x2 pkfma(f32x2 a, f32x2 b, f32x2 c) {
  return __builtin_elementwise_fma(a, b, c);  // v_pk_fma_f32
}

union BF8 { __hip_bfloat162 h[4]; short8 v; unsigned u[4]; };
__device__ inline short8 pack8(float4 a, float4 b) {  // 8 f32 -> 8 bf16 (RNE)
  BF8 r;
  r.h[0] = __float22bfloat162_rn(make_float2(a.x, a.y));
  r.h[1] = __float22bfloat162_rn(make_float2(a.z, a.w));
  r.h[2] = __float22bfloat162_rn(make_float2(b.x, b.y));
  r.h[3] = __float22bfloat162_rn(make_float2(b.z, b.w));
  return r.v;
}

// ---------------------------------------------------------------------------
// K0: pack W (128x128 f32) into bf16 MFMA B-fragment order:
// frag f = kk*8+j, lane l=(L,H): wpk[(f*64+l)*8 + i] = bf16(W[j*16+L][kk*32+H*8+i])
// ---------------------------------------------------------------------------
__global__ __launch_bounds__(256) void wpack_kernel(const float* __restrict__ W,
                                                    ushort* __restrict__ wpk) {
  int task = blockIdx.x * 256 + threadIdx.x;  // 2048 = 32 frags x 64 lanes
  if (task >= 2048) return;
  int f = task >> 6, l = task & 63;
  int kk = f >> 3, j = f & 7, L = l & 15, H = l >> 4;
  const float* src = W + (size_t)(j * 16 + L) * 128 + kk * 32 + H * 8;
  float4 a = *(const float4*)src;
  float4 b = *(const float4*)(src + 4);
  *(short8*)(wpk + (size_t)task * 8) = pack8(a, b);
}

// ---------------------------------------------------------------------------
// K1: z16[r] = bf16(normalize_per_capsule(relu(x @ W^T + b))), row n = 0.
// A-frags straight from global x (f32->bf16 in regs, no LDS, no stage barrier).
// B-frags: coalesced global short8 loads from wpk (identical across waves ->
// L2 broadcast). LDS only for the f32 epilogue transpose (33.8 KB -> 4 blk/CU).
// ---------------------------------------------------------------------------
__global__ __launch_bounds__(256) void fc_mfma_kernel(
    const float* __restrict__ x, const ushort* __restrict__ wpk,
    const float* __restrict__ bias, ushort* __restrict__ z16, int n) {
  __shared__ __align__(16) float ys[TM1 * 132];  // 33792 B

  const int t = threadIdx.x, lane = t & 63, w = t >> 6;
  const int L = lane & 15, H = lane >> 4;
  const int r0 = blockIdx.x * TM1;
  const int row = r0 + w * 16 + L;
  const bool ok = row < n;
  const float4 z4 = make_float4(0.f, 0.f, 0.f, 0.f);

  // A fragments for this wave's 16-row tile, kk = 0..3
  const float* xr = x + (size_t)row * DFULL + H * 8;
  short8 af[4];
#pragma unroll
  for (int kk = 0; kk < 4; ++kk) {
    float4 xa = ok ? *(const float4*)(xr + kk * 32) : z4;
    float4 xb = ok ? *(const float4*)(xr + kk * 32 + 4) : z4;
    af[kk] = pack8(xa, xb);
  }

  f32x4 acc[8];
#pragma unroll
  for (int j = 0; j < 8; ++j) {
    float bv = bias[j * 16 + L];
    acc[j] = (f32x4){bv, bv, bv, bv};
  }
  const short8* wf = (const short8*)wpk;
#pragma unroll
  for (int j = 0; j < 8; ++j) {
#pragma unroll
    for (int kk = 0; kk < 4; ++kk) {
      short8 bfr = wf[(size_t)(kk * 8 + j) * 64 + lane];
      acc[j] = __builtin_amdgcn_mfma_f32_16x16x32_bf16(af[kk], bfr, acc[j], 0, 0, 0);
    }
  }

  // scatter relu'd f32 tile to ys[local_row][d] (stride 132)
  const int lr = w * 16 + H * 4;
#pragma unroll
  for (int j = 0; j < 8; ++j)
#pragma unroll
    for (int r = 0; r < 4; ++r)
      ys[(lr + r) * 132 + j * 16 + L] = fmaxf(acc[j][r], 0.f);
  __syncthreads();

  // norm + bf16 store: 512 (row,capsule) tasks, 2 per thread
#pragma unroll
  for (int pass = 0; pass < 2; ++pass) {
    int task = t + pass * 256;
    int rr = task >> 3, cc = task & 7;
    const float4* yr = (const float4*)(ys + rr * 132 + cc * 16);
    float4 a = yr[0], b = yr[1], c4 = yr[2], d4 = yr[3];
    float ss = a.x * a.x;
    ss = fmaf(a.y, a.y, ss); ss = fmaf(a.z, a.z, ss); ss = fmaf(a.w, a.w, ss);
    ss = fmaf(b.x, b.x, ss); ss = fmaf(b.y, b.y, ss); ss = fmaf(b.z, b.z, ss);
    ss = fmaf(b.w, b.w, ss); ss = fmaf(c4.x, c4.x, ss); ss = fmaf(c4.y, c4.y, ss);
    ss = fmaf(c4.z, c4.z, ss); ss = fmaf(c4.w, c4.w, ss); ss = fmaf(d4.x, d4.x, ss);
    ss = fmaf(d4.y, d4.y, ss); ss = fmaf(d4.z, d4.z, ss); ss = fmaf(d4.w, d4.w, ss);
    float sc = 1.f / fmaxf(sqrtf(ss), 1e-12f);
    int grow = r0 + rr;
    if (grow < n) {
      BF8 o0, o1;
      o0.h[0] = __float22bfloat162_rn(make_float2(a.x * sc, a.y * sc));
      o0.h[1] = __float22bfloat162_rn(make_float2(a.z * sc, a.w * sc));
      o0.h[2] = __float22bfloat162_rn(make_float2(b.x * sc, b.y * sc));
      o0.h[3] = __float22bfloat162_rn(make_float2(b.z * sc, b.w * sc));
      o1.h[0] = __float22bfloat162_rn(make_float2(c4.x * sc, c4.y * sc));
      o1.h[1] = __float22bfloat162_rn(make_float2(c4.z * sc, c4.w * sc));
      o1.h[2] = __float22bfloat162_rn(make_float2(d4.x * sc, d4.y * sc));
      o1.h[3] = __float22bfloat162_rn(make_float2(d4.z * sc, d4.w * sc));
      short8* dst = (short8*)(z16 + (size_t)grow * DFULL + cc * 16);
      dst[0] = o0.v;
      dst[1] = o1.v;
    } else if (grow == n) {  // pad row = zeros
      short8 zz = {0, 0, 0, 0, 0, 0, 0, 0};
      short8* dst = (short8*)(z16 + (size_t)grow * DFULL + cc * 16);
      dst[0] = zz;
      dst[1] = zz;
    }
  }
}

// ---------------------------------------------------------------------------
// K2: routing. 2 nodes/block, node = 2 waves (h = t>>7, g = t&127).
// p-phase: thread (p=g>>3, c=g&7) owns neighbor rows 2p,2p+1 channel c in regs;
//          softmax in-wave via shfl over the 8 c-lanes (no pl, no barrier).
// u-phase: thread d=g; nbT = m-pair-packed bf16 rows (16 dwords + pad, bank-
//          swizzled by 4c) -> 4 ds_read_b128; s read as broadcast b128.
// ---------------------------------------------------------------------------
#define NBS 20   // nbT row stride in dwords (16 data + 4 pad; 80B, 16B-aligned)
#define SLS 36   // slT row stride in floats (144B, 16B-aligned)
#define ULS 20   // ul row stride in floats (80B, 16B-aligned)

__global__ __launch_bounds__(256) void routing_kernel(
    const ushort* __restrict__ z16, const int* __restrict__ nid,
    float* __restrict__ out, int n) {
  __shared__ __align__(16) unsigned nbT[2][DFULL * NBS];   // 2 x 10240 B
  __shared__ __align__(16) float slT[2][CHANNEL * SLS];    // 2 x 1152 B
  __shared__ __align__(16) float ul[2][CHANNEL * ULS];     // 2 x 640 B

  const int t = threadIdx.x;
  const int h = t >> 7, g = t & 127;
  const int node = 2 * blockIdx.x + h;
  const int p = g >> 3, c = g & 7;       // staging / p-phase role
  const int d = g, uc = g >> 4;          // u-phase role

  // ---- stage: load neighbor rows 2p, 2p+1, channel c (16 bf16 each)
  int r0 = nid[node * MNBR + 2 * p];
  int r1 = nid[node * MNBR + 2 * p + 1];
  const uint4* s0 = (const uint4*)(z16 + (size_t)r0 * DFULL + c * KDIM);
  const uint4* s1 = (const uint4*)(z16 + (size_t)r1 * DFULL + c * KDIM);
  uint4 Ra = s0[0], Rb = s0[1];
  uint4 Sa = s1[0], Sb = s1[1];

  // transpose-pack into nbT: dword for k holds (row2p[k] lo16, row2p+1[k] hi16)
  {
    unsigned* nb = nbT[h];
    const int pc = (p + 4 * c) & 15;  // bank swizzle, keeps b128 s-alignment
    unsigned aw[8] = {Ra.x, Ra.y, Ra.z, Ra.w, Rb.x, Rb.y, Rb.z, Rb.w};
    unsigned bw[8] = {Sa.x, Sa.y, Sa.z, Sa.w, Sb.x, Sb.y, Sb.z, Sb.w};
#pragma unroll
    for (int i = 0; i < 8; ++i) {
      unsigned ev = __builtin_amdgcn_perm(bw[i], aw[i], 0x05040100u);  // k=2i
      unsigned od = __builtin_amdgcn_perm(bw[i], aw[i], 0x07060302u);  // k=2i+1
      nb[(c * KDIM + 2 * i) * NBS + pc] = ev;
      nb[(c * KDIM + 2 * i + 1) * NBS + pc] = od;
    }
  }
  const float xk = bf2f(z16[(size_t)node * DFULL + d]);
  ul[h][uc * ULS + (d & 15)] = xk;
  __syncthreads();

  for (int it = 0; it < ROUT_IT; ++it) {
    // ---- p-phase: p[m][c] = <u_c, nb_mc> from regs; e = exp(p) (|p|<=1)
    {
      const f32x4* up = (const f32x4*)(ul[h] + c * ULS);
      f32x4 u0 = up[0], u1 = up[1], u2 = up[2], u3 = up[3];
      f32x2 uu[8] = {{u0.x, u0.y}, {u0.z, u0.w}, {u1.x, u1.y}, {u1.z, u1.w},
                     {u2.x, u2.y}, {u2.z, u2.w}, {u3.x, u3.y}, {u3.z, u3.w}};
      unsigned aw[8] = {Ra.x, Ra.y, Ra.z, Ra.w, Rb.x, Rb.y, Rb.z, Rb.w};
      unsigned bw[8] = {Sa.x, Sa.y, Sa.z, Sa.w, Sb.x, Sb.y, Sb.z, Sb.w};
      f32x2 A0 = {0.f, 0.f}, A1 = {0.f, 0.f};
#pragma unroll
      for (int i = 0; i < 8; ++i) {
        A0 = pkfma((f32x2){bflo(aw[i]), bfhi(aw[i])}, uu[i], A0);
        A1 = pkfma((f32x2){bflo(bw[i]), bfhi(bw[i])}, uu[i], A1);
      }
      float e0 = __expf(A0.x + A0.y);
      float e1 = __expf(A1.x + A1.y);
      // softmax denominator across the 8 c-lanes (lane = p*8 + c)
      float d0 = e0, d1 = e1;
      d0 += __shfl_xor(d0, 1); d1 += __shfl_xor(d1, 1);
      d0 += __shfl_xor(d0, 2); d1 += __shfl_xor(d1, 2);
      d0 += __shfl_xor(d0, 4); d1 += __shfl_xor(d1, 4);
      f32x2 s2 = {e0 * __builtin_amdgcn_rcpf(d0), e1 * __builtin_amdgcn_rcpf(d1)};
      *(f32x2*)(slT[h] + c * SLS + 2 * p) = s2;
    }
    __syncthreads();
    // ---- u-phase: u[d] = xk + sum_m s[m][c]*nb[m][d]
    {
      const unsigned* nr = nbT[h] + d * NBS;
      const float* sr = slT[h] + uc * SLS;
      f32x2 A0 = {0.f, 0.f}, A1 = {0.f, 0.f};
#pragma unroll
      for (int q = 0; q < 4; ++q) {
        uint4 nv = *(const uint4*)(nr + 4 * q);
        int off = 8 * ((q - uc) & 3);  // un-swizzle: m base for this b128
        f32x4 sA = *(const f32x4*)(sr + off);
        f32x4 sB = *(const f32x4*)(sr + off + 4);
        A0 = pkfma((f32x2){bflo(nv.x), bfhi(nv.x)}, (f32x2){sA.x, sA.y}, A0);
        A1 = pkfma((f32x2){bflo(nv.y), bfhi(nv.y)}, (f32x2){sA.z, sA.w}, A1);
        A0 = pkfma((f32x2){bflo(nv.z), bfhi(nv.z)}, (f32x2){sB.x, sB.y}, A0);
        A1 = pkfma((f32x2){bflo(nv.w), bfhi(nv.w)}, (f32x2){sB.z, sB.w}, A1);
      }
      f32x2 S = A0 + A1;
      float u = S.x + S.y + xk;
      if (it == ROUT_IT - 1) {
        out[(size_t)node * DFULL + d] = u;
      } else {
        float ss = u * u;  // capsule norm over the 16 k-lanes
        ss += __shfl_xor(ss, 1);
        ss += __shfl_xor(ss, 2);
        ss += __shfl_xor(ss, 4);
        ss += __shfl_xor(ss, 8);
        float sc = 1.f / fmaxf(sqrtf(ss), 1e-12f);
        ul[h][uc * ULS + (d & 15)] = u * sc;
      }
    }
    __syncthreads();
  }
}

// ---------------------------------------------------------------------------
extern "C" void kernel_launch(void* const* d_in, const int* in_sizes, int n_in,
                              void* d_out, int out_size, void* d_ws, size_t ws_size,
                              hipStream_t stream) {
  const float* x = (const float*)d_in[0];
  const float* W = (const float*)d_in[1];
  const float* b = (const float*)d_in[2];
  const int* nid = (const int*)d_in[3];
  float* out = (float*)d_out;

  int n = in_sizes[0] / DFULL;            // 50000
  int g1 = (n + 1 + TM1 - 1) / TM1;       // 782 (covers rows 0..n)
  size_t zrows = (size_t)g1 * TM1;        // 50048

  ushort* z16 = (ushort*)d_ws;                   // zrows x 128 bf16 table
  ushort* wpk = (ushort*)d_ws + zrows * DFULL;   // 2048 x 8 bf16 W fragments

  wpack_kernel<<<8, 256, 0, stream>>>(W, wpk);
  fc_mfma_kernel<<<g1, 256, 0, stream>>>(x, wpk, b, z16, n);
  routing_kernel<<<n / 2, 256, 0, stream>>>(z16, nid, out, n);
}